// Round 8
// baseline (235.949 us; speedup 1.0000x reference)
//
#include <hip/hip_runtime.h>
#include <math.h>

#define NE 8
#define KDIM 4096
#define PDIM 64
#define WROWS (KDIM + PDIM)   // 4160
#define EPS_F32 1.1920929e-07f
#define NCHUNK 16             // 4096 / (64 lanes * 4 floats)

typedef float f4 __attribute__((ext_vector_type(4)));

// --- tiny setup kernel: W[4160][8] -> Wt[8][4160] in d_ws ---
__global__ __launch_bounds__(256)
void transpose_w(const float* __restrict__ W, float* __restrict__ Wt) {
    const int k = blockIdx.x * 256 + threadIdx.x;
    if (k < WROWS) {
        float v[NE];
#pragma unroll
        for (int e = 0; e < NE; ++e) v[e] = W[(size_t)k * NE + e];
#pragma unroll
        for (int e = 0; e < NE; ++e) Wt[(size_t)e * WROWS + k] = v[e];
    }
}

// Copy-kernel shape: ONE token per wave, wave sweeps its 16KB row LINEARLY.
// Block = 256 thr = 4 waves = 4 consecutive tokens. Grid = 2048 = 8 blocks/CU
// -> 32 waves/CU (full occupancy), whole grid co-resident. VGPR <= 64 via
// __launch_bounds__(256,8). MLP comes from TLP, like the 6.7 TB/s fill.
__global__ __launch_bounds__(256, 8)
void topk_gate(const float* __restrict__ x,
               const float* __restrict__ prompt,
               const float* __restrict__ Wt,
               const float* __restrict__ b,
               float* __restrict__ out,
               int tokens)
{
    const int lane = threadIdx.x & 63;
    const int wave = threadIdx.x >> 6;
    const int tg   = blockIdx.x * 4 + wave;    // this wave's token
    const int klane = lane * 4;

    const float* xrow = x + (size_t)tg * KDIM + klane;

    float acc[NE];
#pragma unroll
    for (int e = 0; e < NE; ++e) acc[e] = 0.f;

    // depth-2 x prefetch, single f4 per slot (8 VGPRs)
    f4 xb[2];
    xb[0] = __builtin_nontemporal_load((const f4*)(xrow));
    xb[1] = __builtin_nontemporal_load((const f4*)(xrow + 256));

#pragma unroll
    for (int c = 0; c < NCHUNK; ++c) {
        const int cur = c & 1;
        const f4 xv = xb[cur];
        if (c + 2 < NCHUNK)
            xb[cur] = __builtin_nontemporal_load((const f4*)(xrow + (c + 2) * 256));

        const int k = c * 256 + klane;
        // expert halves to keep live registers low
#pragma unroll
        for (int eh = 0; eh < 2; ++eh) {
            f4 wv[4];
#pragma unroll
            for (int j = 0; j < 4; ++j)
                wv[j] = *(const f4*)(Wt + (size_t)(eh * 4 + j) * WROWS + k);
#pragma unroll
            for (int j = 0; j < 4; ++j) {
                const int e = eh * 4 + j;
                acc[e] = fmaf(xv.x, wv[j].x, acc[e]);
                acc[e] = fmaf(xv.y, wv[j].y, acc[e]);
                acc[e] = fmaf(xv.z, wv[j].z, acc[e]);
                acc[e] = fmaf(xv.w, wv[j].w, acc[e]);
            }
        }
    }

    // prompt (64 dims): lanes 0..15 cover 4 each; Wt rows 4096..4159 (L2-hot)
    if (lane < 16) {
        const int k = lane * 4;
        const f4 pv = *(const f4*)(prompt + (size_t)tg * PDIM + k);
#pragma unroll
        for (int eh = 0; eh < 2; ++eh) {
            f4 wv[4];
#pragma unroll
            for (int j = 0; j < 4; ++j)
                wv[j] = *(const f4*)(Wt + (size_t)(eh * 4 + j) * WROWS + KDIM + k);
#pragma unroll
            for (int j = 0; j < 4; ++j) {
                const int e = eh * 4 + j;
                acc[e] = fmaf(pv.x, wv[j].x, acc[e]);
                acc[e] = fmaf(pv.y, wv[j].y, acc[e]);
                acc[e] = fmaf(pv.z, wv[j].z, acc[e]);
                acc[e] = fmaf(pv.w, wv[j].w, acc[e]);
            }
        }
    }

    // butterfly reduce: every lane ends with the token's full 8 logits
#pragma unroll
    for (int e = 0; e < NE; ++e) {
        float v = acc[e];
#pragma unroll
        for (int off = 32; off >= 1; off >>= 1)
            v += __shfl_xor(v, off, 64);
        acc[e] = v;
    }

    float lg[NE];
#pragma unroll
    for (int e = 0; e < NE; ++e) lg[e] = acc[e] + b[e];

    // top-2, strict > so smallest index wins ties (jax.lax.top_k semantics)
    float v0 = lg[0]; int i0 = 0;
#pragma unroll
    for (int e = 1; e < NE; ++e)
        if (lg[e] > v0) { v0 = lg[e]; i0 = e; }
    float v1 = (i0 == 0) ? lg[1] : lg[0];
    int   i1 = (i0 == 0) ? 1 : 0;
#pragma unroll
    for (int e = 0; e < NE; ++e)
        if (e != i0 && lg[e] > v1) { v1 = lg[e]; i1 = e; }

    float s = 0.f;
#pragma unroll
    for (int e = 0; e < NE; ++e) s += __expf(lg[e] - v0);
    const float g0 = 1.0f / s;
    const float g1 = __expf(v1 - v0) / s;
    const float denom = fmaxf(g0 + g1, EPS_F32);

    // masks: lanes 0..15 write out[tg*16 + lane] (kk = lane>>3, ee = lane&7)
    if (lane < 16) {
        const int kk  = lane >> 3;
        const int ee  = lane & 7;
        const int sel = kk ? i1 : i0;
        out[(size_t)tg * 16 + lane] = (ee == sel) ? 1.0f : 0.0f;
    }
    // gates: lane 0 -> slot 0, lane 8 -> slot 1
    if (lane == 0)
        out[(size_t)tokens * 16 + (size_t)tg * 2 + 0] = g0 / denom;
    if (lane == 8)
        out[(size_t)tokens * 16 + (size_t)tg * 2 + 1] = g1 / denom;
}

extern "C" void kernel_launch(void* const* d_in, const int* in_sizes, int n_in,
                              void* d_out, int out_size, void* d_ws, size_t ws_size,
                              hipStream_t stream) {
    const float* x      = (const float*)d_in[0];
    const float* prompt = (const float*)d_in[1];
    const float* W      = (const float*)d_in[2];
    const float* b      = (const float*)d_in[3];
    float* out          = (float*)d_out;
    float* Wt           = (float*)d_ws;          // 8*4160*4 = 133 KB

    const int tokens = in_sizes[0] / KDIM;       // 8192

    hipLaunchKernelGGL(transpose_w, dim3((WROWS + 255) / 256), dim3(256), 0, stream,
                       W, Wt);
    hipLaunchKernelGGL(topk_gate, dim3(tokens / 4), dim3(256), 0, stream,
                       x, prompt, Wt, b, out, tokens);
}